// Round 5
// baseline (422.593 us; speedup 1.0000x reference)
//
#include <hip/hip_runtime.h>
#include <hip/hip_bf16.h>
#include <stdint.h>

typedef __attribute__((ext_vector_type(4))) float f32x4;
typedef __attribute__((ext_vector_type(8))) short s16x8;

#define XS_STRIDE 68   // 64 cols + 2 pad each side; also the ht stride (aliased buffer)
#define AS_STRIDE 132  // 32-left-pad + 64 + 36-right-pad; covers +-30 halo, no guards
#define AS_OFF 32
#define HT_STRIDE 68

__device__ static inline void load_lds_16B(const void* g, void* l) {
    __builtin_amdgcn_global_load_lds((const __attribute__((address_space(1))) void*)g,
                                     (__attribute__((address_space(3))) void*)l,
                                     16, 0, 0);
}

// force a block-uniform value into an SGPR (weights/biases are per-channel,
// c is blockIdx-derived -> genuinely uniform; keeps them out of the VGPR budget)
__device__ static inline float uload(const float* p) {
    return __uint_as_float(__builtin_amdgcn_readfirstlane(__float_as_uint(*p)));
}

// ---------------- Kernel 1: fused depthwise chain, one (n,c) plane per block ----------------
// 512 threads, 50 KB LDS. Scatter-accumulate: stream each LDS window element
// once, FMA into the <=3 accumulators it feeds (j == k mod 3).
// amdgpu_waves_per_eu(6,6): pin the scheduler's occupancy target (launch_bounds'
// 2nd arg is a MIN -> range [N,8] -> scheduler chased 8 waves/EU and spilled at
// a 64-VGPR budget in rounds 2-4). 6 waves/EU = 3 blocks/CU (= the 50KB LDS
// limit), hard VGPR budget 512/6 ~= 85.

template<int K, int P>
__device__ __forceinline__ void branch_h(const float* __restrict__ wh, float bh,
                                         int r, int cq,
                                         const float* as_, float* ht_) {
    constexpr int NW = 2 * P + 8;          // window width for 8 outputs
    constexpr int SH = (AS_OFF - P) & 3;   // alignment shift (cq is 8-aligned)
    constexpr int NV = (SH + NW + 3) / 4;  // f32x4 loads
    float wr[K];
#pragma unroll
    for (int i = 0; i < K; ++i) wr[i] = uload(wh + i);   // SGPR
    float a[8];
#pragma unroll
    for (int j = 0; j < 8; ++j) a[j] = bh;
    const float* base = as_ + r * AS_STRIDE + (AS_OFF - P - SH) + cq;  // 16B aligned
#pragma unroll
    for (int v = 0; v < NV; ++v) {
        f32x4 q = *(const f32x4*)(base + 4 * v);
#pragma unroll
        for (int e4 = 0; e4 < 4; ++e4) {
            const int k = v * 4 + e4 - SH;     // compile-time constant
            if (k >= 0 && k < NW) {
#pragma unroll
                for (int j = (k % 3); j < 8; j += 3) {
                    const int i = (k - j) / 3;
                    if (i >= 0 && i < K) a[j] += q[e4] * wr[i];
                }
            }
        }
    }
#pragma unroll
    for (int i = 0; i < 2; ++i) {
        f32x4 o = {a[4 * i], a[4 * i + 1], a[4 * i + 2], a[4 * i + 3]};
        *(f32x4*)(ht_ + r * HT_STRIDE + cq + 4 * i) = o;
    }
}

template<int K, int P>
__device__ __forceinline__ void branch_v(const float* __restrict__ wv, float bv,
                                         int cc, int r0,
                                         const float* ht_, float* ss) {
    constexpr int NW = 2 * P + 8;
    float wr[K];
#pragma unroll
    for (int i = 0; i < K; ++i) wr[i] = uload(wv + i);   // SGPR
    float a[8];
#pragma unroll
    for (int j = 0; j < 8; ++j) a[j] = bv;
#pragma unroll
    for (int k = 0; k < NW; ++k) {
        const int rr = r0 - P + k;               // wave-uniform
        const float val = (rr >= 0 && rr < 64) ? ht_[rr * HT_STRIDE + cc] : 0.0f;
#pragma unroll
        for (int j = (k % 3); j < 8; j += 3) {
            const int i = (k - j) / 3;
            if (i >= 0 && i < K) a[j] += val * wr[i];
        }
    }
#pragma unroll
    for (int j = 0; j < 8; ++j) ss[j] += a[j];
}

__global__ __launch_bounds__(512)
__attribute__((amdgpu_waves_per_eu(6, 6)))
void k1_dw(const float* __restrict__ x,
           const float* __restrict__ w0,   const float* __restrict__ b0,
           const float* __restrict__ w0_1, const float* __restrict__ b0_1,
           const float* __restrict__ w0_2, const float* __restrict__ b0_2,
           const float* __restrict__ w1_1, const float* __restrict__ b1_1,
           const float* __restrict__ w1_2, const float* __restrict__ b1_2,
           const float* __restrict__ w2_1, const float* __restrict__ b2_1,
           const float* __restrict__ w2_2, const float* __restrict__ b2_2,
           __hip_bfloat16* __restrict__ s_out) {
    __shared__ float as[64 * AS_STRIDE];     // 33.8 KB
    __shared__ float xs_ht[64 * XS_STRIDE];  // 17.4 KB: xs for phases 0-1, ht afterwards

    const int t = threadIdx.x;
    const int bid = blockIdx.x;
    const int c = bid & 511;
    const size_t pbase = (size_t)bid * 4096;

    // zero 'as' fully (covers halo pads); zero xs pad cols
    {
        f32x4 z = {0.f, 0.f, 0.f, 0.f};
        f32x4* asv = (f32x4*)as;
#pragma unroll
        for (int i = 0; i < 5; ++i) {
            int idx = t + i * 512;
            if (idx < 64 * AS_STRIDE / 4) asv[idx] = z;
        }
        if (t < 64) {
            xs_ht[t * XS_STRIDE + 0] = 0.f; xs_ht[t * XS_STRIDE + 1] = 0.f;
            xs_ht[t * XS_STRIDE + 66] = 0.f; xs_ht[t * XS_STRIDE + 67] = 0.f;
        }
    }
    const int r = t >> 3, cq = (t & 7) * 8;    // row ownership (h-phases): 8 px/thread
    // load x plane
    {
        const f32x4* gx = (const f32x4*)(x + pbase + r * 64 + cq);
        f32x4* dst = (f32x4*)(xs_ht + r * XS_STRIDE + 2 + cq);
        dst[0] = gx[0]; dst[1] = gx[1];
    }
    __syncthreads();

    // Phase 1: 5x5 depthwise, pad 2
    {
        const float bias = uload(b0 + c);
        float acc[8];
#pragma unroll
        for (int j = 0; j < 8; ++j) acc[j] = bias;
        const float* wc = w0 + c * 25;
        float wr[25];
#pragma unroll
        for (int i = 0; i < 25; ++i) wr[i] = uload(wc + i);   // SGPR
#pragma unroll
        for (int dr = 0; dr < 5; ++dr) {
            int rr = r + dr - 2;
            if (rr >= 0 && rr <= 63) {
                float v[12];
                const float* src = xs_ht + rr * XS_STRIDE + cq;  // padded: col cq-2 at +0
#pragma unroll
                for (int i = 0; i < 3; ++i) {
                    f32x4 tmp = *(const f32x4*)(src + 4 * i);
                    v[4 * i + 0] = tmp[0]; v[4 * i + 1] = tmp[1];
                    v[4 * i + 2] = tmp[2]; v[4 * i + 3] = tmp[3];
                }
#pragma unroll
                for (int j = 0; j < 8; ++j)
#pragma unroll
                    for (int dc = 0; dc < 5; ++dc)
                        acc[j] += v[j + dc] * wr[dr * 5 + dc];
            }
        }
#pragma unroll
        for (int i = 0; i < 2; ++i) {
            f32x4 o = {acc[4 * i], acc[4 * i + 1], acc[4 * i + 2], acc[4 * i + 3]};
            *(f32x4*)(as + r * AS_STRIDE + AS_OFF + cq + 4 * i) = o;
        }
    }
    __syncthreads();   // as ready; xs dead -> buffer becomes ht

    const int cc = t & 63, r0 = (t >> 6) * 8;  // column ownership (v-phases): 8 px/thread

    float ss[8];
#pragma unroll
    for (int j = 0; j < 8; ++j) ss[j] = as[(r0 + j) * AS_STRIDE + AS_OFF + cc];

    branch_h<7, 9>(w0_1 + c * 7, uload(b0_1 + c), r, cq, as, xs_ht);
    __syncthreads();
    branch_v<7, 9>(w0_2 + c * 7, uload(b0_2 + c), cc, r0, xs_ht, ss);
    __syncthreads();
    branch_h<11, 15>(w1_1 + c * 11, uload(b1_1 + c), r, cq, as, xs_ht);
    __syncthreads();
    branch_v<11, 15>(w1_2 + c * 11, uload(b1_2 + c), cc, r0, xs_ht, ss);
    __syncthreads();
    branch_h<21, 30>(w2_1 + c * 21, uload(b2_1 + c), r, cq, as, xs_ht);
    __syncthreads();
    branch_v<21, 30>(w2_2 + c * 21, uload(b2_2 + c), cc, r0, xs_ht, ss);

#pragma unroll
    for (int j = 0; j < 8; ++j)
        s_out[pbase + (size_t)(r0 + j) * 64 + cc] = __float2bfloat16(ss[j]);
}

// ---------------- Kernel 2: transpose s [n][ci][px] -> st [n][px][ci] (bf16) ----------------
__global__ __launch_bounds__(256, 4)
void k2_transpose(const __hip_bfloat16* __restrict__ s_px,
                  __hip_bfloat16* __restrict__ st) {
    __shared__ short tile[64][66];
    const int b = blockIdx.x;
    const int n = b >> 9, rem = b & 511;
    const int cib = rem >> 6, pxb = rem & 63;
    const int t = threadIdx.x;

    {
        const int row = t >> 2, chunk = (t & 3) * 16;
        const __hip_bfloat16* src =
            s_px + ((size_t)(n * 512 + cib * 64 + row)) * 4096 + pxb * 64 + chunk;
        s16x8 v0 = *(const s16x8*)(src);
        s16x8 v1 = *(const s16x8*)(src + 8);
#pragma unroll
        for (int k = 0; k < 8; ++k) {
            tile[row][chunk + k] = v0[k];
            tile[row][chunk + 8 + k] = v1[k];
        }
    }
    __syncthreads();
    {
        const int pxl = t >> 2, cich = (t & 3) * 16;
        s16x8 o0, o1;
#pragma unroll
        for (int k = 0; k < 8; ++k) {
            o0[k] = tile[cich + k][pxl];
            o1[k] = tile[cich + 8 + k][pxl];
        }
        __hip_bfloat16* dst =
            st + ((size_t)(n * 4096 + pxb * 64 + pxl)) * 512 + cib * 64 + cich;
        *(s16x8*)dst = o0;
        *(s16x8*)(dst + 8) = o1;
    }
}

// ---------------- Kernel 2b: cast w3 fp32 -> bf16 ----------------
__global__ __launch_bounds__(256, 4)
void k2b_cast(const float* __restrict__ w3, __hip_bfloat16* __restrict__ w3b) {
    const int i = (blockIdx.x * 256 + threadIdx.x) * 4;
    f32x4 v = *(const f32x4*)(w3 + i);
    union { __hip_bfloat16 h[4]; uint32_t u[2]; } pk;
#pragma unroll
    for (int k = 0; k < 4; ++k) pk.h[k] = __float2bfloat16(v[k]);
    *(uint32_t*)((char*)(w3b + i)) = pk.u[0];
    *(uint32_t*)((char*)(w3b + i) + 4) = pk.u[1];
}

// ---------------- Kernel 3: bf16 MFMA GEMM (m97 structure) + fused epilogue ----------------
// out[n,co,px] = (sum_ci w3[co,ci]*s[n,ci,px] + b3[co]) * x[n,co,px]
__global__ __launch_bounds__(256, 2)
void k3_gemm(const __hip_bfloat16* __restrict__ w3b,
             const __hip_bfloat16* __restrict__ st,
             const float* __restrict__ b3,
             const float* __restrict__ x,
             float* __restrict__ out) {
    __shared__ __hip_bfloat16 As[128 * 64];  // [co_local][k] k-major
    __shared__ __hip_bfloat16 Bs[128 * 64];  // [px_local][k] k-major

    const int t = threadIdx.x;
    const int lane = t & 63, wv = t >> 6;
    const int waveM = wv & 1, waveN = wv >> 1;
    const int coBase = blockIdx.x * 128;
    const int nb = blockIdx.y;
    const int n = nb >> 5, pxTile = nb & 31;
    const int pxBase = pxTile * 128;
    const int lr = lane & 15, lq = lane >> 4;

    f32x4 acc[4][4] = {};

    for (int k0 = 0; k0 < 512; k0 += 64) {
#pragma unroll
        for (int s = 0; s < 4; ++s) {
            const int seg = wv * 4 + s;
            const int rowg = seg * 8 + (lane >> 3);
            const int kcol = k0 + (lane & 7) * 8;
            const __hip_bfloat16* ga = w3b + (size_t)(coBase + rowg) * 512 + kcol;
            load_lds_16B(ga, &As[seg * 512]);
            const __hip_bfloat16* gb =
                st + ((size_t)(n * 4096 + pxBase + rowg)) * 512 + kcol;
            load_lds_16B(gb, &Bs[seg * 512]);
        }
        __syncthreads();
#pragma unroll
        for (int kk = 0; kk < 64; kk += 32) {
            s16x8 af[4], bf[4];
#pragma unroll
            for (int m = 0; m < 4; ++m)
                af[m] = *(const s16x8*)&As[(waveM * 64 + m * 16 + lr) * 64 + kk + lq * 8];
#pragma unroll
            for (int nn = 0; nn < 4; ++nn)
                bf[nn] = *(const s16x8*)&Bs[(waveN * 64 + nn * 16 + lr) * 64 + kk + lq * 8];
#pragma unroll
            for (int m = 0; m < 4; ++m)
#pragma unroll
                for (int nn = 0; nn < 4; ++nn)
                    acc[m][nn] = __builtin_amdgcn_mfma_f32_16x16x32_bf16(
                        af[m], bf[nn], acc[m][nn], 0, 0, 0);
        }
        __syncthreads();
    }

    // epilogue: D[r=co][c=px], row=(lane>>4)*4+reg, col=lane&15
#pragma unroll
    for (int m = 0; m < 4; ++m) {
#pragma unroll
        for (int nn = 0; nn < 4; ++nn) {
            const int px = pxBase + waveN * 64 + nn * 16 + lr;
#pragma unroll
            for (int j = 0; j < 4; ++j) {
                const int co = coBase + waveM * 64 + m * 16 + lq * 4 + j;
                const size_t idx = ((size_t)(n * 512 + co)) * 4096 + px;
                out[idx] = (acc[m][nn][j] + b3[co]) * x[idx];
            }
        }
    }
}

extern "C" void kernel_launch(void* const* d_in, const int* in_sizes, int n_in,
                              void* d_out, int out_size, void* d_ws, size_t ws_size,
                              hipStream_t stream) {
    (void)in_sizes; (void)n_in; (void)out_size; (void)ws_size;
    const float* x    = (const float*)d_in[0];
    const float* w0   = (const float*)d_in[1];
    const float* b0   = (const float*)d_in[2];
    const float* w0_1 = (const float*)d_in[3];
    const float* b0_1 = (const float*)d_in[4];
    const float* w0_2 = (const float*)d_in[5];
    const float* b0_2 = (const float*)d_in[6];
    const float* w1_1 = (const float*)d_in[7];
    const float* b1_1 = (const float*)d_in[8];
    const float* w1_2 = (const float*)d_in[9];
    const float* b1_2 = (const float*)d_in[10];
    const float* w2_1 = (const float*)d_in[11];
    const float* b2_1 = (const float*)d_in[12];
    const float* w2_2 = (const float*)d_in[13];
    const float* b2_2 = (const float*)d_in[14];
    const float* w3   = (const float*)d_in[15];
    const float* b3   = (const float*)d_in[16];
    float* out = (float*)d_out;

    // scratch layout: s (bf16, 32 MiB) lives in the front half of d_out (dead
    // before k3 writes out); st (bf16, 32 MiB) + w3b (512 KiB) in d_ws.
    __hip_bfloat16* s_px = (__hip_bfloat16*)d_out;
    __hip_bfloat16* st   = (__hip_bfloat16*)d_ws;
    __hip_bfloat16* w3b  = (__hip_bfloat16*)((char*)d_ws + ((size_t)32 << 20));

    k1_dw<<<4096, 512, 0, stream>>>(x, w0, b0, w0_1, b0_1, w0_2, b0_2,
                                    w1_1, b1_1, w1_2, b1_2, w2_1, b2_1,
                                    w2_2, b2_2, s_px);
    k2_transpose<<<4096, 256, 0, stream>>>(s_px, st);
    k2b_cast<<<256, 256, 0, stream>>>(w3, w3b);
    k3_gemm<<<dim3(4, 256), 256, 0, stream>>>(w3b, st, b3, x, out);
}

// Round 6
// 273.037 us; speedup vs baseline: 1.5478x; 1.5478x over previous
//
#include <hip/hip_runtime.h>
#include <hip/hip_bf16.h>
#include <stdint.h>

typedef __attribute__((ext_vector_type(4))) float f32x4;
typedef __attribute__((ext_vector_type(8))) short s16x8;

#define XS_STRIDE 68   // 64 cols + 2 pad each side; also ht stride (aliased buffer)
#define AS_STRIDE 132  // 32-left-pad + 64 + 36-right-pad; covers +-30 halo, no guards
#define AS_OFF 32
#define HT_STRIDE 68

__device__ static inline void load_lds_16B(const void* g, void* l) {
    __builtin_amdgcn_global_load_lds((const __attribute__((address_space(1))) void*)g,
                                     (__attribute__((address_space(3))) void*)l,
                                     16, 0, 0);
}

// ---------------- Kernel 1: fused depthwise chain, one (n,c) plane per block ----------------
// LESSON (rounds 2-5): every 512-thread variant spilled (allocator chased max
// occupancy, capped VGPR at 40-64, 0.6-1.3 GB scratch traffic). The only
// no-spill config is round-1's: 256 threads, 16 px/thread, launch_bounds(256,2)
// -> VGPR=128, FETCH~ideal. This round: that exact config + xs/ht LDS aliasing
// (67KB -> 50KB) so residency rises 2 -> 3 blocks/CU (8 -> 12 waves/CU).

template<int K, int P, int P4>
__device__ __forceinline__ void branch_h(const float* __restrict__ wh, float bh,
                                         int r, int cq,
                                         const float* as_, float* ht_) {
    constexpr int SH = P4 - P;
    constexpr int NW = 16 + 2 * P;
    constexpr int NV = (NW + SH + 3) / 4;
    float vb[NV * 4];
    const float* src = as_ + r * AS_STRIDE + (AS_OFF - P4) + cq;  // 16B aligned
#pragma unroll
    for (int i = 0; i < NV; ++i) {
        f32x4 tmp = *(const f32x4*)(src + 4 * i);
        vb[4 * i + 0] = tmp[0]; vb[4 * i + 1] = tmp[1];
        vb[4 * i + 2] = tmp[2]; vb[4 * i + 3] = tmp[3];
    }
    float wr[K];
#pragma unroll
    for (int i = 0; i < K; ++i) wr[i] = wh[i];   // uniform -> s_load
    float out[16];
#pragma unroll
    for (int j = 0; j < 16; ++j) {
        float a = bh;
#pragma unroll
        for (int i = 0; i < K; ++i) a += vb[SH + j + 3 * i] * wr[i];
        out[j] = a;
    }
#pragma unroll
    for (int i = 0; i < 4; ++i) {
        f32x4 o = {out[4 * i], out[4 * i + 1], out[4 * i + 2], out[4 * i + 3]};
        *(f32x4*)(ht_ + r * HT_STRIDE + cq + 4 * i) = o;
    }
}

template<int K, int P>
__device__ __forceinline__ void branch_v(const float* __restrict__ wv, float bv,
                                         int cc, int r0,
                                         const float* ht_, float* ss) {
    constexpr int NW = 16 + 2 * P;
    float u[NW];
#pragma unroll
    for (int k = 0; k < NW; ++k) {
        int rr = r0 - P + k;
        u[k] = (rr >= 0 && rr < 64) ? ht_[rr * HT_STRIDE + cc] : 0.0f;
    }
    float wr[K];
#pragma unroll
    for (int i = 0; i < K; ++i) wr[i] = wv[i];
#pragma unroll
    for (int j = 0; j < 16; ++j) {
        float a = bv;
#pragma unroll
        for (int i = 0; i < K; ++i) a += u[j + 3 * i] * wr[i];
        ss[j] += a;
    }
}

__global__ __launch_bounds__(256, 2)
void k1_dw(const float* __restrict__ x,
           const float* __restrict__ w0,   const float* __restrict__ b0,
           const float* __restrict__ w0_1, const float* __restrict__ b0_1,
           const float* __restrict__ w0_2, const float* __restrict__ b0_2,
           const float* __restrict__ w1_1, const float* __restrict__ b1_1,
           const float* __restrict__ w1_2, const float* __restrict__ b1_2,
           const float* __restrict__ w2_1, const float* __restrict__ b2_1,
           const float* __restrict__ w2_2, const float* __restrict__ b2_2,
           __hip_bfloat16* __restrict__ s_out) {
    __shared__ float as[64 * AS_STRIDE];     // 33.8 KB
    __shared__ float xs_ht[64 * XS_STRIDE];  // 17.4 KB: xs for phases 0-1, ht afterwards

    const int t = threadIdx.x;
    const int bid = blockIdx.x;
    const int c = bid & 511;
    const size_t pbase = (size_t)bid * 4096;

    // zero 'as' fully (covers halo pads); zero xs pad cols
    {
        f32x4 z = {0.f, 0.f, 0.f, 0.f};
        f32x4* asv = (f32x4*)as;
#pragma unroll
        for (int i = 0; i < 9; ++i) {
            int idx = t + i * 256;
            if (idx < 64 * AS_STRIDE / 4) asv[idx] = z;
        }
        if (t < 64) {
            xs_ht[t * XS_STRIDE + 0] = 0.f; xs_ht[t * XS_STRIDE + 1] = 0.f;
            xs_ht[t * XS_STRIDE + 66] = 0.f; xs_ht[t * XS_STRIDE + 67] = 0.f;
        }
    }
    // load x plane: thread t -> row r = t>>2, 16-col chunk
    {
        const int r = t >> 2, cq = (t & 3) * 16;
        const f32x4* gx = (const f32x4*)(x + pbase + r * 64 + cq);
        f32x4* dst = (f32x4*)(xs_ht + r * XS_STRIDE + 2 + cq);
#pragma unroll
        for (int i = 0; i < 4; ++i) dst[i] = gx[i];
    }
    __syncthreads();

    // Phase 1: 5x5 depthwise, pad 2 (cross-correlation)
    {
        const int r = t >> 2, cq = (t & 3) * 16;
        const float bias = b0[c];
        float acc[16];
#pragma unroll
        for (int j = 0; j < 16; ++j) acc[j] = bias;
        const float* wc = w0 + c * 25;
#pragma unroll
        for (int dr = 0; dr < 5; ++dr) {
            int rr = r + dr - 2;
            if (rr >= 0 && rr <= 63) {
                float v[20];
                const float* src = xs_ht + rr * XS_STRIDE + cq;  // padded: col cq-2 at +0
#pragma unroll
                for (int i = 0; i < 5; ++i) {
                    f32x4 tmp = *(const f32x4*)(src + 4 * i);
                    v[4 * i + 0] = tmp[0]; v[4 * i + 1] = tmp[1];
                    v[4 * i + 2] = tmp[2]; v[4 * i + 3] = tmp[3];
                }
                const float* wrow = wc + dr * 5;
#pragma unroll
                for (int j = 0; j < 16; ++j)
#pragma unroll
                    for (int dc = 0; dc < 5; ++dc)
                        acc[j] += v[j + dc] * wrow[dc];
            }
        }
#pragma unroll
        for (int i = 0; i < 4; ++i) {
            f32x4 o = {acc[4 * i], acc[4 * i + 1], acc[4 * i + 2], acc[4 * i + 3]};
            *(f32x4*)(as + r * AS_STRIDE + AS_OFF + cq + 4 * i) = o;
        }
    }
    __syncthreads();   // as ready; xs dead -> buffer becomes ht

    const int r = t >> 2, cq = (t & 3) * 16;   // row ownership (h-phases)
    const int cc = t & 63, r0 = (t >> 6) * 16; // column ownership (v-phases)

    float ss[16];
#pragma unroll
    for (int j = 0; j < 16; ++j) ss[j] = as[(r0 + j) * AS_STRIDE + AS_OFF + cc];

    branch_h<7, 9, 12>(w0_1 + c * 7, b0_1[c], r, cq, as, xs_ht);
    __syncthreads();
    branch_v<7, 9>(w0_2 + c * 7, b0_2[c], cc, r0, xs_ht, ss);
    __syncthreads();
    branch_h<11, 15, 16>(w1_1 + c * 11, b1_1[c], r, cq, as, xs_ht);
    __syncthreads();
    branch_v<11, 15>(w1_2 + c * 11, b1_2[c], cc, r0, xs_ht, ss);
    __syncthreads();
    branch_h<21, 30, 32>(w2_1 + c * 21, b2_1[c], r, cq, as, xs_ht);
    __syncthreads();
    branch_v<21, 30>(w2_2 + c * 21, b2_2[c], cc, r0, xs_ht, ss);

#pragma unroll
    for (int j = 0; j < 16; ++j)
        s_out[pbase + (size_t)(r0 + j) * 64 + cc] = __float2bfloat16(ss[j]);
}

// ---------------- Kernel 2: transpose s [n][ci][px] -> st [n][px][ci] (bf16) ----------------
__global__ __launch_bounds__(256, 4)
void k2_transpose(const __hip_bfloat16* __restrict__ s_px,
                  __hip_bfloat16* __restrict__ st) {
    __shared__ short tile[64][66];
    const int b = blockIdx.x;
    const int n = b >> 9, rem = b & 511;
    const int cib = rem >> 6, pxb = rem & 63;
    const int t = threadIdx.x;

    {
        const int row = t >> 2, chunk = (t & 3) * 16;
        const __hip_bfloat16* src =
            s_px + ((size_t)(n * 512 + cib * 64 + row)) * 4096 + pxb * 64 + chunk;
        s16x8 v0 = *(const s16x8*)(src);
        s16x8 v1 = *(const s16x8*)(src + 8);
#pragma unroll
        for (int k = 0; k < 8; ++k) {
            tile[row][chunk + k] = v0[k];
            tile[row][chunk + 8 + k] = v1[k];
        }
    }
    __syncthreads();
    {
        const int pxl = t >> 2, cich = (t & 3) * 16;
        s16x8 o0, o1;
#pragma unroll
        for (int k = 0; k < 8; ++k) {
            o0[k] = tile[cich + k][pxl];
            o1[k] = tile[cich + 8 + k][pxl];
        }
        __hip_bfloat16* dst =
            st + ((size_t)(n * 4096 + pxb * 64 + pxl)) * 512 + cib * 64 + cich;
        *(s16x8*)dst = o0;
        *(s16x8*)(dst + 8) = o1;
    }
}

// ---------------- Kernel 2b: cast w3 fp32 -> bf16 ----------------
__global__ __launch_bounds__(256, 4)
void k2b_cast(const float* __restrict__ w3, __hip_bfloat16* __restrict__ w3b) {
    const int i = (blockIdx.x * 256 + threadIdx.x) * 4;
    f32x4 v = *(const f32x4*)(w3 + i);
    union { __hip_bfloat16 h[4]; uint32_t u[2]; } pk;
#pragma unroll
    for (int k = 0; k < 4; ++k) pk.h[k] = __float2bfloat16(v[k]);
    *(uint32_t*)((char*)(w3b + i)) = pk.u[0];
    *(uint32_t*)((char*)(w3b + i) + 4) = pk.u[1];
}

// ---------------- Kernel 3: bf16 MFMA GEMM (m97 structure) + fused epilogue ----------------
// out[n,co,px] = (sum_ci w3[co,ci]*s[n,ci,px] + b3[co]) * x[n,co,px]
__global__ __launch_bounds__(256, 2)
void k3_gemm(const __hip_bfloat16* __restrict__ w3b,
             const __hip_bfloat16* __restrict__ st,
             const float* __restrict__ b3,
             const float* __restrict__ x,
             float* __restrict__ out) {
    __shared__ __hip_bfloat16 As[128 * 64];  // [co_local][k] k-major
    __shared__ __hip_bfloat16 Bs[128 * 64];  // [px_local][k] k-major

    const int t = threadIdx.x;
    const int lane = t & 63, wv = t >> 6;
    const int waveM = wv & 1, waveN = wv >> 1;
    const int coBase = blockIdx.x * 128;
    const int nb = blockIdx.y;
    const int n = nb >> 5, pxTile = nb & 31;
    const int pxBase = pxTile * 128;
    const int lr = lane & 15, lq = lane >> 4;

    f32x4 acc[4][4] = {};

    for (int k0 = 0; k0 < 512; k0 += 64) {
#pragma unroll
        for (int s = 0; s < 4; ++s) {
            const int seg = wv * 4 + s;
            const int rowg = seg * 8 + (lane >> 3);
            const int kcol = k0 + (lane & 7) * 8;
            const __hip_bfloat16* ga = w3b + (size_t)(coBase + rowg) * 512 + kcol;
            load_lds_16B(ga, &As[seg * 512]);
            const __hip_bfloat16* gb =
                st + ((size_t)(n * 4096 + pxBase + rowg)) * 512 + kcol;
            load_lds_16B(gb, &Bs[seg * 512]);
        }
        __syncthreads();
#pragma unroll
        for (int kk = 0; kk < 64; kk += 32) {
            s16x8 af[4], bf[4];
#pragma unroll
            for (int m = 0; m < 4; ++m)
                af[m] = *(const s16x8*)&As[(waveM * 64 + m * 16 + lr) * 64 + kk + lq * 8];
#pragma unroll
            for (int nn = 0; nn < 4; ++nn)
                bf[nn] = *(const s16x8*)&Bs[(waveN * 64 + nn * 16 + lr) * 64 + kk + lq * 8];
#pragma unroll
            for (int m = 0; m < 4; ++m)
#pragma unroll
                for (int nn = 0; nn < 4; ++nn)
                    acc[m][nn] = __builtin_amdgcn_mfma_f32_16x16x32_bf16(
                        af[m], bf[nn], acc[m][nn], 0, 0, 0);
        }
        __syncthreads();
    }

    // epilogue: D[r=co][c=px], row=(lane>>4)*4+reg, col=lane&15
#pragma unroll
    for (int m = 0; m < 4; ++m) {
#pragma unroll
        for (int nn = 0; nn < 4; ++nn) {
            const int px = pxBase + waveN * 64 + nn * 16 + lr;
#pragma unroll
            for (int j = 0; j < 4; ++j) {
                const int co = coBase + waveM * 64 + m * 16 + lq * 4 + j;
                const size_t idx = ((size_t)(n * 512 + co)) * 4096 + px;
                out[idx] = (acc[m][nn][j] + b3[co]) * x[idx];
            }
        }
    }
}

extern "C" void kernel_launch(void* const* d_in, const int* in_sizes, int n_in,
                              void* d_out, int out_size, void* d_ws, size_t ws_size,
                              hipStream_t stream) {
    (void)in_sizes; (void)n_in; (void)out_size; (void)ws_size;
    const float* x    = (const float*)d_in[0];
    const float* w0   = (const float*)d_in[1];
    const float* b0   = (const float*)d_in[2];
    const float* w0_1 = (const float*)d_in[3];
    const float* b0_1 = (const float*)d_in[4];
    const float* w0_2 = (const float*)d_in[5];
    const float* b0_2 = (const float*)d_in[6];
    const float* w1_1 = (const float*)d_in[7];
    const float* b1_1 = (const float*)d_in[8];
    const float* w1_2 = (const float*)d_in[9];
    const float* b1_2 = (const float*)d_in[10];
    const float* w2_1 = (const float*)d_in[11];
    const float* b2_1 = (const float*)d_in[12];
    const float* w2_2 = (const float*)d_in[13];
    const float* b2_2 = (const float*)d_in[14];
    const float* w3   = (const float*)d_in[15];
    const float* b3   = (const float*)d_in[16];
    float* out = (float*)d_out;

    // scratch layout: s (bf16, 32 MiB) lives in the front half of d_out (dead
    // before k3 writes out); st (bf16, 32 MiB) + w3b (512 KiB) in d_ws.
    __hip_bfloat16* s_px = (__hip_bfloat16*)d_out;
    __hip_bfloat16* st   = (__hip_bfloat16*)d_ws;
    __hip_bfloat16* w3b  = (__hip_bfloat16*)((char*)d_ws + ((size_t)32 << 20));

    k1_dw<<<4096, 256, 0, stream>>>(x, w0, b0, w0_1, b0_1, w0_2, b0_2,
                                    w1_1, b1_1, w1_2, b1_2, w2_1, b2_1,
                                    w2_2, b2_2, s_px);
    k2_transpose<<<4096, 256, 0, stream>>>(s_px, st);
    k2b_cast<<<256, 256, 0, stream>>>(w3, w3b);
    k3_gemm<<<dim3(4, 256), 256, 0, stream>>>(w3b, st, b3, x, out);
}